// Round 1
// baseline (588.275 us; speedup 1.0000x reference)
//
#include <hip/hip_runtime.h>

// DensityGridNN: 3-stage Lorentzian projection + trilinear upsample chain.
// B=8, N=64 nodes, E=128 feats, C=32 channels; grids 16^3 -> 32^3 -> 64^3.

constexpr int NB = 8;
constexpr int NNODE = 64;
constexpr int NE = 128;
constexpr int NC = 32;

// nf[s][b][n][c] = sum_e node_features[b][n][e] * Wp[s][e][c] + bp[s][c]
__global__ void nf_kernel(const float* __restrict__ node_features, // (8,64,128)
                          const float* __restrict__ Wp,            // (3,128,32)
                          const float* __restrict__ bp,            // (3,32)
                          float* __restrict__ nf)                  // (3,8,64,32)
{
    int idx = blockIdx.x * 256 + threadIdx.x;     // < 3*8*64*32 = 49152 exactly
    int c = idx & (NC - 1);
    int n = (idx >> 5) & (NNODE - 1);
    int b = (idx >> 11) & (NB - 1);
    int s = idx >> 14;
    const float* f = node_features + (b * NNODE + n) * NE;
    const float* w = Wp + s * NE * NC + c;
    float acc = bp[s * NC + c];
#pragma unroll 8
    for (int e = 0; e < NE; ++e)
        acc = fmaf(f[e], w[e * NC], acc);
    nf[idx] = acc;
}

// One thread per grid point; 32 channels accumulated in registers.
// STAGE>0 fuses the 2x trilinear upsample (half-pixel, edge-clamped == jax
// normalized weights) of the previous stage's grid as an 8-tap epilogue.
template <int STAGE, int NX>
__global__ __launch_bounds__(256) void stage_kernel(
        const float* __restrict__ pos,         // (8,64,3)
        const float* __restrict__ origin,      // (8,3)
        const float* __restrict__ lattice,     // (8,3,3)
        const int*   __restrict__ batch_nodes, // (8,)
        const float* __restrict__ scale,       // (3,)
        const float* __restrict__ nf,          // (3,8,64,32)
        const float* __restrict__ prev,        // (8,32,(NX/2)^3) or null
        float* __restrict__ outp)              // (8,32,NX^3)
{
    constexpr int LOG = (NX == 16) ? 4 : (NX == 32) ? 5 : 6;
    constexpr int G = NX * NX * NX;
    constexpr int TPB = G / 256;

    const int b = blockIdx.x / TPB;
    const int g = (blockIdx.x % TPB) * 256 + threadIdx.x;

    const int iz = g & (NX - 1);
    const int iy = (g >> LOG) & (NX - 1);
    const int ix = g >> (2 * LOG);

    // linspace(0, l, NX): step l/(NX-1); grid point + origin[b]
    const float llx = lattice[0], lly = lattice[4], llz = lattice[8];
    const float stx = llx / (float)(NX - 1);
    const float sty = lly / (float)(NX - 1);
    const float stz = llz / (float)(NX - 1);
    const float gx = fmaf((float)ix, stx, origin[b * 3 + 0]);
    const float gy = fmaf((float)iy, sty, origin[b * 3 + 1]);
    const float gz = fmaf((float)iz, stz, origin[b * 3 + 2]);
    const float g2 = fmaf(gx, gx, fmaf(gy, gy, gz * gz));

    const float s  = scale[STAGE];
    const float s2 = s * s;
    const int nn = batch_nodes[b];

    float acc[NC];
#pragma unroll
    for (int c = 0; c < NC; ++c) acc[c] = 0.0f;

    const float* __restrict__ prow = pos + b * NNODE * 3;
    const float* __restrict__ nrow = nf + (STAGE * NB + b) * NNODE * NC;

    for (int n = 0; n < nn; ++n) {
        // wave-uniform addresses -> scalar loads
        const float px = prow[n * 3 + 0];
        const float py = prow[n * 3 + 1];
        const float pz = prow[n * 3 + 2];
        const float p2 = fmaf(px, px, fmaf(py, py, pz * pz));
        const float dot = fmaf(gx, px, fmaf(gy, py, gz * pz));
        float d2 = fmaf(-2.0f, dot, g2 + p2);
        d2 = fmaxf(d2, 0.0f);
        const float w = s * __builtin_amdgcn_rcpf(s2 + d2);
        const float* __restrict__ r = nrow + n * NC;
#pragma unroll
        for (int c = 0; c < NC; ++c)
            acc[c] = fmaf(w, r[c], acc[c]);
    }

    float* __restrict__ o = outp + (size_t)(b * NC) * G + g;

    if constexpr (STAGE == 0) {
#pragma unroll
        for (int c = 0; c < NC; ++c) o[(size_t)c * G] = acc[c];
    } else {
        constexpr int NH = NX / 2;
        constexpr int GH = NH * NH * NH;
        // half-pixel 2x upsample taps: even o -> (m-1,m)@(0.25,0.75);
        // odd o -> (m,m+1)@(0.75,0.25); edge-clamped.
        int x0i = (ix >> 1) - 1 + (ix & 1); int x1i = x0i + 1;
        int y0i = (iy >> 1) - 1 + (iy & 1); int y1i = y0i + 1;
        int z0i = (iz >> 1) - 1 + (iz & 1); int z1i = z0i + 1;
        const float wxl = (ix & 1) ? 0.75f : 0.25f;
        const float wyl = (iy & 1) ? 0.75f : 0.25f;
        const float wzl = (iz & 1) ? 0.75f : 0.25f;
        if (x0i < 0) x0i = 0; if (x1i > NH - 1) x1i = NH - 1;
        if (y0i < 0) y0i = 0; if (y1i > NH - 1) y1i = NH - 1;
        if (z0i < 0) z0i = 0; if (z1i > NH - 1) z1i = NH - 1;
        const float wxh = 1.0f - wxl, wyh = 1.0f - wyl, wzh = 1.0f - wzl;

        const int o000 = (x0i * NH + y0i) * NH + z0i;
        const int o001 = (x0i * NH + y0i) * NH + z1i;
        const int o010 = (x0i * NH + y1i) * NH + z0i;
        const int o011 = (x0i * NH + y1i) * NH + z1i;
        const int o100 = (x1i * NH + y0i) * NH + z0i;
        const int o101 = (x1i * NH + y0i) * NH + z1i;
        const int o110 = (x1i * NH + y1i) * NH + z0i;
        const int o111 = (x1i * NH + y1i) * NH + z1i;

        const float w000 = wxl * wyl * wzl, w001 = wxl * wyl * wzh;
        const float w010 = wxl * wyh * wzl, w011 = wxl * wyh * wzh;
        const float w100 = wxh * wyl * wzl, w101 = wxh * wyl * wzh;
        const float w110 = wxh * wyh * wzl, w111 = wxh * wyh * wzh;

        const float* __restrict__ pb = prev + (size_t)(b * NC) * GH;
#pragma unroll
        for (int c = 0; c < NC; ++c) {
            const float* __restrict__ pc = pb + (size_t)c * GH;
            float up = w000 * pc[o000] + w001 * pc[o001]
                     + w010 * pc[o010] + w011 * pc[o011]
                     + w100 * pc[o100] + w101 * pc[o101]
                     + w110 * pc[o110] + w111 * pc[o111];
            o[(size_t)c * G] = up + acc[c];
        }
    }
}

extern "C" void kernel_launch(void* const* d_in, const int* in_sizes, int n_in,
                              void* d_out, int out_size, void* d_ws, size_t ws_size,
                              hipStream_t stream) {
    const float* pos           = (const float*)d_in[0];
    const float* node_features = (const float*)d_in[1];
    const float* origin        = (const float*)d_in[2];
    const float* lattice       = (const float*)d_in[3];
    const int*   batch_nodes   = (const int*)d_in[4];
    const float* Wp            = (const float*)d_in[5];
    const float* bp            = (const float*)d_in[6];
    const float* scale         = (const float*)d_in[7];
    float* out = (float*)d_out;

    float* wsf = (float*)d_ws;
    float* nf = wsf;                                   // 3*8*64*32 = 49152 floats
    float* x0 = wsf + 49152;                           // 8*32*4096  = 1048576
    float* x1 = x0 + (size_t)NB * NC * 16 * 16 * 16;   // 8*32*32768 = 8388608

    nf_kernel<<<dim3(192), dim3(256), 0, stream>>>(node_features, Wp, bp, nf);

    stage_kernel<0, 16><<<dim3(NB * 16), dim3(256), 0, stream>>>(
        pos, origin, lattice, batch_nodes, scale, nf, (const float*)nullptr, x0);

    stage_kernel<1, 32><<<dim3(NB * 128), dim3(256), 0, stream>>>(
        pos, origin, lattice, batch_nodes, scale, nf, x0, x1);

    stage_kernel<2, 64><<<dim3(NB * 1024), dim3(256), 0, stream>>>(
        pos, origin, lattice, batch_nodes, scale, nf, x1, out);
}

// Round 2
// 542.307 us; speedup vs baseline: 1.0848x; 1.0848x over previous
//
#include <hip/hip_runtime.h>

// DensityGridNN: 3-stage Lorentzian projection + trilinear upsample chain.
// B=8, N=64 nodes, E=128 feats, C=32 channels; grids 16^3 -> 32^3 -> 64^3.

constexpr int NB = 8;
constexpr int NNODE = 64;
constexpr int NE = 128;
constexpr int NC = 32;

// nf[s][b][n][c] = (sum_e node_features[b][n][e] * Wp[s][e][c] + bp[s][c]) * scale[s]
// scale folded in so the stage kernels use w = rcp(denom) with no extra mul.
__global__ void nf_kernel(const float* __restrict__ node_features, // (8,64,128)
                          const float* __restrict__ Wp,            // (3,128,32)
                          const float* __restrict__ bp,            // (3,32)
                          const float* __restrict__ scale,         // (3,)
                          float* __restrict__ nf)                  // (3,8,64,32)
{
    int idx = blockIdx.x * 256 + threadIdx.x;     // < 3*8*64*32 = 49152 exactly
    int c = idx & (NC - 1);
    int n = (idx >> 5) & (NNODE - 1);
    int b = (idx >> 11) & (NB - 1);
    int s = idx >> 14;
    const float* f = node_features + (b * NNODE + n) * NE;
    const float* w = Wp + s * NE * NC + c;
    float acc = bp[s * NC + c];
#pragma unroll 8
    for (int e = 0; e < NE; ++e)
        acc = fmaf(f[e], w[e * NC], acc);
    nf[idx] = acc * scale[s];
}

// One thread per grid point; 32 channels accumulated in registers.
// nf (pre-scaled) and folded pos live in LDS; in-loop reads are wave-uniform
// broadcast ds_read_b128 (conflict-free).
// STAGE>0 fuses the 2x trilinear upsample (half-pixel, edge-clamped == jax
// normalized weights) of the previous stage's grid as an 8-tap epilogue.
template <int STAGE, int NX>
__global__ __launch_bounds__(256) void stage_kernel(
        const float* __restrict__ pos,         // (8,64,3)
        const float* __restrict__ origin,      // (8,3)
        const float* __restrict__ lattice,     // (8,3,3)
        const int*   __restrict__ batch_nodes, // (8,)
        const float* __restrict__ scale,       // (3,)
        const float* __restrict__ nf,          // (3,8,64,32) pre-scaled
        const float* __restrict__ prev,        // (8,32,(NX/2)^3) or null
        float* __restrict__ outp)              // (8,32,NX^3)
{
    constexpr int LOG = (NX == 16) ? 4 : (NX == 32) ? 5 : 6;
    constexpr int G = NX * NX * NX;
    constexpr int TPB = G / 256;

    __shared__ float4 nfs[NNODE][NC / 4];  // 8 KB
    __shared__ float4 poss[NNODE];         // 1 KB: (-2px,-2py,-2pz,p2)

    const int b = blockIdx.x / TPB;
    const int g = (blockIdx.x % TPB) * 256 + threadIdx.x;

    // stage LDS
    const float* __restrict__ nrow = nf + (STAGE * NB + b) * NNODE * NC;
    {
        const float4* n4 = reinterpret_cast<const float4*>(nrow);
        int t = threadIdx.x;
        nfs[t >> 3][t & 7] = n4[t];
        t += 256;
        nfs[t >> 3][t & 7] = n4[t];
        if (threadIdx.x < NNODE) {
            const float* p = pos + (b * NNODE + threadIdx.x) * 3;
            float px = p[0], py = p[1], pz = p[2];
            poss[threadIdx.x] = make_float4(-2.0f * px, -2.0f * py, -2.0f * pz,
                                            fmaf(px, px, fmaf(py, py, pz * pz)));
        }
    }

    const int iz = g & (NX - 1);
    const int iy = (g >> LOG) & (NX - 1);
    const int ix = g >> (2 * LOG);

    // linspace(0, l, NX): step l/(NX-1); grid point + origin[b]
    const float stx = lattice[0] / (float)(NX - 1);
    const float sty = lattice[4] / (float)(NX - 1);
    const float stz = lattice[8] / (float)(NX - 1);
    const float gx = fmaf((float)ix, stx, origin[b * 3 + 0]);
    const float gy = fmaf((float)iy, sty, origin[b * 3 + 1]);
    const float gz = fmaf((float)iz, stz, origin[b * 3 + 2]);

    const float s  = scale[STAGE];
    const float s2 = s * s;
    const float g2s2 = fmaf(gx, gx, fmaf(gy, gy, fmaf(gz, gz, s2)));
    const int nn = batch_nodes[b];

    float acc[NC];
#pragma unroll
    for (int c = 0; c < NC; ++c) acc[c] = 0.0f;

    __syncthreads();

#pragma unroll 2
    for (int n = 0; n < nn; ++n) {
        const float4 pq = poss[n];
        float t = fmaf(pq.x, gx, pq.w);
        t = fmaf(pq.y, gy, t);
        t = fmaf(pq.z, gz, t);
        // denom = s2 + max(d2,0) where d2 = t + g2;  == max(t+g2+s2, s2)
        const float denom = fmaxf(t + g2s2, s2);
        const float w = __builtin_amdgcn_rcpf(denom);
#pragma unroll
        for (int c4 = 0; c4 < NC / 4; ++c4) {
            const float4 v = nfs[n][c4];
            acc[c4 * 4 + 0] = fmaf(w, v.x, acc[c4 * 4 + 0]);
            acc[c4 * 4 + 1] = fmaf(w, v.y, acc[c4 * 4 + 1]);
            acc[c4 * 4 + 2] = fmaf(w, v.z, acc[c4 * 4 + 2]);
            acc[c4 * 4 + 3] = fmaf(w, v.w, acc[c4 * 4 + 3]);
        }
    }

    float* __restrict__ o = outp + (size_t)(b * NC) * G + g;

    if constexpr (STAGE == 0) {
#pragma unroll
        for (int c = 0; c < NC; ++c) o[(size_t)c * G] = acc[c];
    } else {
        constexpr int NH = NX / 2;
        constexpr int GH = NH * NH * NH;
        // half-pixel 2x upsample taps: even o -> (m-1,m)@(0.25,0.75);
        // odd o -> (m,m+1)@(0.75,0.25); edge-clamped.
        int x0i = (ix >> 1) - 1 + (ix & 1); int x1i = x0i + 1;
        int y0i = (iy >> 1) - 1 + (iy & 1); int y1i = y0i + 1;
        int z0i = (iz >> 1) - 1 + (iz & 1); int z1i = z0i + 1;
        const float wxl = (ix & 1) ? 0.75f : 0.25f;
        const float wyl = (iy & 1) ? 0.75f : 0.25f;
        const float wzl = (iz & 1) ? 0.75f : 0.25f;
        if (x0i < 0) x0i = 0; if (x1i > NH - 1) x1i = NH - 1;
        if (y0i < 0) y0i = 0; if (y1i > NH - 1) y1i = NH - 1;
        if (z0i < 0) z0i = 0; if (z1i > NH - 1) z1i = NH - 1;
        const float wxh = 1.0f - wxl, wyh = 1.0f - wyl, wzh = 1.0f - wzl;

        const int o000 = (x0i * NH + y0i) * NH + z0i;
        const int o001 = (x0i * NH + y0i) * NH + z1i;
        const int o010 = (x0i * NH + y1i) * NH + z0i;
        const int o011 = (x0i * NH + y1i) * NH + z1i;
        const int o100 = (x1i * NH + y0i) * NH + z0i;
        const int o101 = (x1i * NH + y0i) * NH + z1i;
        const int o110 = (x1i * NH + y1i) * NH + z0i;
        const int o111 = (x1i * NH + y1i) * NH + z1i;

        const float w000 = wxl * wyl * wzl, w001 = wxl * wyl * wzh;
        const float w010 = wxl * wyh * wzl, w011 = wxl * wyh * wzh;
        const float w100 = wxh * wyl * wzl, w101 = wxh * wyl * wzh;
        const float w110 = wxh * wyh * wzl, w111 = wxh * wyh * wzh;

        const float* __restrict__ pb = prev + (size_t)(b * NC) * GH;
#pragma unroll
        for (int c = 0; c < NC; ++c) {
            const float* __restrict__ pc = pb + (size_t)c * GH;
            float up = w000 * pc[o000] + w001 * pc[o001]
                     + w010 * pc[o010] + w011 * pc[o011]
                     + w100 * pc[o100] + w101 * pc[o101]
                     + w110 * pc[o110] + w111 * pc[o111];
            float r = up + acc[c];
            if constexpr (STAGE == 2)
                __builtin_nontemporal_store(r, &o[(size_t)c * G]);
            else
                o[(size_t)c * G] = r;
        }
    }
}

extern "C" void kernel_launch(void* const* d_in, const int* in_sizes, int n_in,
                              void* d_out, int out_size, void* d_ws, size_t ws_size,
                              hipStream_t stream) {
    const float* pos           = (const float*)d_in[0];
    const float* node_features = (const float*)d_in[1];
    const float* origin        = (const float*)d_in[2];
    const float* lattice       = (const float*)d_in[3];
    const int*   batch_nodes   = (const int*)d_in[4];
    const float* Wp            = (const float*)d_in[5];
    const float* bp            = (const float*)d_in[6];
    const float* scale         = (const float*)d_in[7];
    float* out = (float*)d_out;

    float* wsf = (float*)d_ws;
    float* nf = wsf;                                   // 3*8*64*32 = 49152 floats
    float* x0 = wsf + 49152;                           // 8*32*4096  = 1048576
    float* x1 = x0 + (size_t)NB * NC * 16 * 16 * 16;   // 8*32*32768 = 8388608

    nf_kernel<<<dim3(192), dim3(256), 0, stream>>>(node_features, Wp, bp, scale, nf);

    stage_kernel<0, 16><<<dim3(NB * 16), dim3(256), 0, stream>>>(
        pos, origin, lattice, batch_nodes, scale, nf, (const float*)nullptr, x0);

    stage_kernel<1, 32><<<dim3(NB * 128), dim3(256), 0, stream>>>(
        pos, origin, lattice, batch_nodes, scale, nf, x0, x1);

    stage_kernel<2, 64><<<dim3(NB * 1024), dim3(256), 0, stream>>>(
        pos, origin, lattice, batch_nodes, scale, nf, x1, out);
}

// Round 10
// 478.954 us; speedup vs baseline: 1.2282x; 1.1323x over previous
//
#include <hip/hip_runtime.h>

// DensityGridNN: 3-stage Lorentzian projection + trilinear upsample chain.
// B=8, N=64 nodes, E=128 feats, C=32 channels; grids 16^3 -> 32^3 -> 64^3.
//
// R3: KG=4 grid points (consecutive z) per thread. Rationale: R2 was
// LDS-pipe bound (9x ds_read_b128 per wave-node = 108 cyc vs 74 cyc VALU;
// model 276us ~= measured 252us). Amortizing nf reads over 4x more output
// work drops LDS to ~69us and VALU to ~47us for stage 2.
// R9 fix: __builtin_nontemporal_store needs a native vector type, not
// HIP_vector_type float4 -> use ext_vector_type alias for the NT store.

constexpr int NB = 8;
constexpr int NNODE = 64;
constexpr int NE = 128;
constexpr int NC = 32;
constexpr int KG = 4;  // grid points per thread (along z)

typedef float f32x4 __attribute__((ext_vector_type(4)));

// nf[s][b][n][c] = (sum_e node_features[b][n][e] * Wp[s][e][c] + bp[s][c]) * scale[s]
__global__ void nf_kernel(const float* __restrict__ node_features, // (8,64,128)
                          const float* __restrict__ Wp,            // (3,128,32)
                          const float* __restrict__ bp,            // (3,32)
                          const float* __restrict__ scale,         // (3,)
                          float* __restrict__ nf)                  // (3,8,64,32)
{
    int idx = blockIdx.x * 256 + threadIdx.x;     // < 3*8*64*32 = 49152 exactly
    int c = idx & (NC - 1);
    int n = (idx >> 5) & (NNODE - 1);
    int b = (idx >> 11) & (NB - 1);
    int s = idx >> 14;
    const float* f = node_features + (b * NNODE + n) * NE;
    const float* w = Wp + s * NE * NC + c;
    float acc = bp[s * NC + c];
#pragma unroll 8
    for (int e = 0; e < NE; ++e)
        acc = fmaf(f[e], w[e * NC], acc);
    nf[idx] = acc * scale[s];
}

// One thread -> KG=4 consecutive-z grid points x 32 channels in registers.
// nf (pre-scaled) + folded pos in LDS, broadcast ds_read_b128.
// STAGE>0 fuses the 2x trilinear upsample of prev (half-pixel, edge-clamped).
template <int STAGE, int NX>
__global__ __launch_bounds__(256, 3) void stage_kernel(
        const float* __restrict__ pos,         // (8,64,3)
        const float* __restrict__ origin,      // (8,3)
        const float* __restrict__ lattice,     // (8,3,3)
        const int*   __restrict__ batch_nodes, // (8,)
        const float* __restrict__ scale,       // (3,)
        const float* __restrict__ nf,          // (3,8,64,32) pre-scaled
        const float* __restrict__ prev,        // (8,32,(NX/2)^3) or null
        float* __restrict__ outp)              // (8,32,NX^3)
{
    constexpr int LOG = (NX == 16) ? 4 : (NX == 32) ? 5 : 6;
    constexpr int G = NX * NX * NX;
    constexpr int NZB = NX / KG;               // z-blocks per z-line

    __shared__ float4 nfs[NNODE][NC / 4];  // 8 KB
    __shared__ float4 poss[NNODE];         // 1 KB: (-2px,-2py,-2pz,p2)

    const int gid = blockIdx.x * 256 + threadIdx.x;
    const int b = gid >> (3 * LOG - 2);        // uniform per block
    const int izb = gid & (NZB - 1);
    const int iy = (gid >> (LOG - 2)) & (NX - 1);
    const int ix = (gid >> (2 * LOG - 2)) & (NX - 1);
    const int iz0 = izb * KG;

    // stage LDS
    const float* __restrict__ nrow = nf + (STAGE * NB + b) * NNODE * NC;
    {
        const float4* n4 = reinterpret_cast<const float4*>(nrow);
        int t = threadIdx.x;
        nfs[t >> 3][t & 7] = n4[t];
        t += 256;
        nfs[t >> 3][t & 7] = n4[t];
        if (threadIdx.x < NNODE) {
            const float* p = pos + (b * NNODE + threadIdx.x) * 3;
            float px = p[0], py = p[1], pz = p[2];
            poss[threadIdx.x] = make_float4(-2.0f * px, -2.0f * py, -2.0f * pz,
                                            fmaf(px, px, fmaf(py, py, pz * pz)));
        }
    }

    // linspace(0, l, NX): step l/(NX-1); grid point + origin[b]
    const float stx = lattice[0] / (float)(NX - 1);
    const float sty = lattice[4] / (float)(NX - 1);
    const float stz = lattice[8] / (float)(NX - 1);
    const float gx = fmaf((float)ix, stx, origin[b * 3 + 0]);
    const float gy = fmaf((float)iy, sty, origin[b * 3 + 1]);
    const float s  = scale[STAGE];
    const float s2 = s * s;
    const float gxy2 = fmaf(gx, gx, fmaf(gy, gy, s2));

    float gz[KG], g2s2[KG];
#pragma unroll
    for (int j = 0; j < KG; ++j) {
        gz[j] = fmaf((float)(iz0 + j), stz, origin[b * 3 + 2]);
        g2s2[j] = fmaf(gz[j], gz[j], gxy2);
    }

    const int nn = batch_nodes[b];

    float acc[KG][NC];
#pragma unroll
    for (int j = 0; j < KG; ++j)
#pragma unroll
        for (int c = 0; c < NC; ++c) acc[j][c] = 0.0f;

    __syncthreads();

#pragma unroll 2
    for (int n = 0; n < nn; ++n) {
        const float4 pq = poss[n];
        const float txy = fmaf(pq.x, gx, fmaf(pq.y, gy, pq.w));
        float w[KG];
#pragma unroll
        for (int j = 0; j < KG; ++j) {
            const float t = fmaf(pq.z, gz[j], txy);
            // denom = s2 + max(d2,0) == max(t + g2 + s2, s2)
            w[j] = __builtin_amdgcn_rcpf(fmaxf(t + g2s2[j], s2));
        }
#pragma unroll
        for (int c4 = 0; c4 < NC / 4; ++c4) {
            const float4 v = nfs[n][c4];
#pragma unroll
            for (int j = 0; j < KG; ++j) {
                acc[j][c4 * 4 + 0] = fmaf(w[j], v.x, acc[j][c4 * 4 + 0]);
                acc[j][c4 * 4 + 1] = fmaf(w[j], v.y, acc[j][c4 * 4 + 1]);
                acc[j][c4 * 4 + 2] = fmaf(w[j], v.z, acc[j][c4 * 4 + 2]);
                acc[j][c4 * 4 + 3] = fmaf(w[j], v.w, acc[j][c4 * 4 + 3]);
            }
        }
    }

    // output base: (b, c, ix, iy, iz0)
    float* __restrict__ o = outp + (size_t)(b * NC) * G + ((ix << LOG) + iy) * NX + iz0;

    if constexpr (STAGE == 0) {
#pragma unroll
        for (int c = 0; c < NC; ++c) {
            float4 r = make_float4(acc[0][c], acc[1][c], acc[2][c], acc[3][c]);
            *reinterpret_cast<float4*>(&o[(size_t)c * G]) = r;
        }
    } else {
        constexpr int NH = NX / 2;
        constexpr int GH = NH * NH * NH;
        // half-pixel 2x upsample: even o -> (m-1,m)@(0.25,0.75);
        // odd o -> (m,m+1)@(0.75,0.25); edge-clamped.
        int x0i = (ix >> 1) - 1 + (ix & 1); int x1i = x0i + 1;
        int y0i = (iy >> 1) - 1 + (iy & 1); int y1i = y0i + 1;
        const float wxl = (ix & 1) ? 0.75f : 0.25f;
        const float wyl = (iy & 1) ? 0.75f : 0.25f;
        if (x0i < 0) x0i = 0; if (x1i > NH - 1) x1i = NH - 1;
        if (y0i < 0) y0i = 0; if (y1i > NH - 1) y1i = NH - 1;
        const float wxh = 1.0f - wxl, wyh = 1.0f - wyl;
        const float w00 = wxl * wyl, w01 = wxl * wyh;
        const float w10 = wxh * wyl, w11 = wxh * wyh;

        // distinct z sources for outputs iz0..iz0+3 (iz0 = 4k):
        // zs = clamp(2k-1 .. 2k+2); outputs:
        // j0: .25*v[0] + .75*v[1]; j1: .75*v[1] + .25*v[2];
        // j2: .25*v[1] + .75*v[2]; j3: .75*v[2] + .25*v[3]
        const int k2 = iz0 >> 1;  // 2k
        int zs[4];
        zs[0] = k2 - 1 < 0 ? 0 : k2 - 1;
        zs[1] = k2;
        zs[2] = k2 + 1;
        zs[3] = k2 + 2 > NH - 1 ? NH - 1 : k2 + 2;

        const int r00 = (x0i * NH + y0i) * NH;
        const int r01 = (x0i * NH + y1i) * NH;
        const int r10 = (x1i * NH + y0i) * NH;
        const int r11 = (x1i * NH + y1i) * NH;

        const float* __restrict__ pb = prev + (size_t)(b * NC) * GH;
#pragma unroll
        for (int c = 0; c < NC; ++c) {
            const float* __restrict__ pc = pb + (size_t)c * GH;
            float v[4];
#pragma unroll
            for (int zi = 0; zi < 4; ++zi) {
                const int z = zs[zi];
                v[zi] = w00 * pc[r00 + z] + w01 * pc[r01 + z]
                      + w10 * pc[r10 + z] + w11 * pc[r11 + z];
            }
            f32x4 r;
            r.x = fmaf(0.25f, v[0], fmaf(0.75f, v[1], acc[0][c]));
            r.y = fmaf(0.75f, v[1], fmaf(0.25f, v[2], acc[1][c]));
            r.z = fmaf(0.25f, v[1], fmaf(0.75f, v[2], acc[2][c]));
            r.w = fmaf(0.75f, v[2], fmaf(0.25f, v[3], acc[3][c]));
            if constexpr (STAGE == 2)
                __builtin_nontemporal_store(r, reinterpret_cast<f32x4*>(&o[(size_t)c * G]));
            else
                *reinterpret_cast<f32x4*>(&o[(size_t)c * G]) = r;
        }
    }
}

extern "C" void kernel_launch(void* const* d_in, const int* in_sizes, int n_in,
                              void* d_out, int out_size, void* d_ws, size_t ws_size,
                              hipStream_t stream) {
    const float* pos           = (const float*)d_in[0];
    const float* node_features = (const float*)d_in[1];
    const float* origin        = (const float*)d_in[2];
    const float* lattice       = (const float*)d_in[3];
    const int*   batch_nodes   = (const int*)d_in[4];
    const float* Wp            = (const float*)d_in[5];
    const float* bp            = (const float*)d_in[6];
    const float* scale         = (const float*)d_in[7];
    float* out = (float*)d_out;

    float* wsf = (float*)d_ws;
    float* nf = wsf;                                   // 3*8*64*32 = 49152 floats
    float* x0 = wsf + 49152;                           // 8*32*4096  = 1048576
    float* x1 = x0 + (size_t)NB * NC * 16 * 16 * 16;   // 8*32*32768 = 8388608

    nf_kernel<<<dim3(192), dim3(256), 0, stream>>>(node_features, Wp, bp, scale, nf);

    stage_kernel<0, 16><<<dim3(NB * 4096 / KG / 256), dim3(256), 0, stream>>>(
        pos, origin, lattice, batch_nodes, scale, nf, (const float*)nullptr, x0);

    stage_kernel<1, 32><<<dim3(NB * 32768 / KG / 256), dim3(256), 0, stream>>>(
        pos, origin, lattice, batch_nodes, scale, nf, x0, x1);

    stage_kernel<2, 64><<<dim3(NB * 262144 / KG / 256), dim3(256), 0, stream>>>(
        pos, origin, lattice, batch_nodes, scale, nf, x1, out);
}

// Round 11
// 440.810 us; speedup vs baseline: 1.3345x; 1.0865x over previous
//
#include <hip/hip_runtime.h>

// DensityGridNN: 3-stage Lorentzian projection + trilinear upsample chain.
// B=8, N=64 nodes, E=128 feats, C=32 channels; grids 16^3 -> 32^3 -> 64^3.
//
// R11: drop LDS staging in stage_kernel. All inner-loop nf/pos addresses are
// wave-uniform (b from blockIdx only, n loop var) -> compiler emits s_load
// (scalar pipe + K$), fmaf takes the nf operand from SGPR. Removes both the
// LDS-pipe throughput term (9x ds_read_b128/node) and ds_read latency that
// ~3 waves/SIMD couldn't hide. pos pre-folded to (-2p, p^2) in ws.

constexpr int NB = 8;
constexpr int NNODE = 64;
constexpr int NE = 128;
constexpr int NC = 32;
constexpr int KG = 4;  // grid points per thread (along z)

typedef float f32x4 __attribute__((ext_vector_type(4)));

// nf[s][b][n][c] = (sum_e node_features[b][n][e] * Wp[s][e][c] + bp[s][c]) * scale[s]
// Also folds pos into posf[b][n] = (-2px,-2py,-2pz,p2).
__global__ void nf_kernel(const float* __restrict__ node_features, // (8,64,128)
                          const float* __restrict__ Wp,            // (3,128,32)
                          const float* __restrict__ bp,            // (3,32)
                          const float* __restrict__ scale,         // (3,)
                          const float* __restrict__ pos,           // (8,64,3)
                          float* __restrict__ nf,                  // (3,8,64,32)
                          float* __restrict__ posf)                // (8,64,4)
{
    int idx = blockIdx.x * 256 + threadIdx.x;     // < 3*8*64*32 = 49152 exactly
    int c = idx & (NC - 1);
    int n = (idx >> 5) & (NNODE - 1);
    int b = (idx >> 11) & (NB - 1);
    int s = idx >> 14;
    const float* f = node_features + (b * NNODE + n) * NE;
    const float* w = Wp + s * NE * NC + c;
    float acc = bp[s * NC + c];
#pragma unroll 8
    for (int e = 0; e < NE; ++e)
        acc = fmaf(f[e], w[e * NC], acc);
    nf[idx] = acc * scale[s];

    if (idx < NB * NNODE) {
        const float* p = pos + idx * 3;
        float px = p[0], py = p[1], pz = p[2];
        f32x4 q;
        q.x = -2.0f * px; q.y = -2.0f * py; q.z = -2.0f * pz;
        q.w = fmaf(px, px, fmaf(py, py, pz * pz));
        *reinterpret_cast<f32x4*>(&posf[idx * 4]) = q;
    }
}

// One thread -> KG=4 consecutive-z grid points x 32 channels in registers.
// nf (pre-scaled) + folded pos read via wave-uniform addresses -> s_load.
// STAGE>0 fuses the 2x trilinear upsample of prev (half-pixel, edge-clamped).
template <int STAGE, int NX>
__global__ __launch_bounds__(256, 3) void stage_kernel(
        const float* __restrict__ posf,        // (8,64,4) folded
        const float* __restrict__ origin,      // (8,3)
        const float* __restrict__ lattice,     // (8,3,3)
        const int*   __restrict__ batch_nodes, // (8,)
        const float* __restrict__ scale,       // (3,)
        const float* __restrict__ nf,          // (3,8,64,32) pre-scaled
        const float* __restrict__ prev,        // (8,32,(NX/2)^3) or null
        float* __restrict__ outp)              // (8,32,NX^3)
{
    constexpr int LOG = (NX == 16) ? 4 : (NX == 32) ? 5 : 6;
    constexpr int G = NX * NX * NX;
    constexpr int NZB = NX / KG;               // z-blocks per z-line
    constexpr int TPBLK = (G / KG) / 256;      // blocks per batch entry

    const int b = blockIdx.x / TPBLK;          // uniform: blockIdx only
    const int wid = (blockIdx.x % TPBLK) * 256 + threadIdx.x;
    const int izb = wid & (NZB - 1);
    const int iy = (wid / NZB) & (NX - 1);
    const int ix = wid / (NZB * NX);
    const int iz0 = izb * KG;

    // linspace(0, l, NX): step l/(NX-1); grid point + origin[b]
    const float stx = lattice[0] / (float)(NX - 1);
    const float sty = lattice[4] / (float)(NX - 1);
    const float stz = lattice[8] / (float)(NX - 1);
    const float gx = fmaf((float)ix, stx, origin[b * 3 + 0]);
    const float gy = fmaf((float)iy, sty, origin[b * 3 + 1]);
    const float s  = scale[STAGE];
    const float s2 = s * s;
    const float gxy2 = fmaf(gx, gx, fmaf(gy, gy, s2));

    float gz[KG], g2s2[KG];
#pragma unroll
    for (int j = 0; j < KG; ++j) {
        gz[j] = fmaf((float)(iz0 + j), stz, origin[b * 3 + 2]);
        g2s2[j] = fmaf(gz[j], gz[j], gxy2);
    }

    const int nn = batch_nodes[b];

    float acc[KG][NC];
#pragma unroll
    for (int j = 0; j < KG; ++j)
#pragma unroll
        for (int c = 0; c < NC; ++c) acc[j][c] = 0.0f;

    const float* __restrict__ nrow = nf + (STAGE * NB + b) * NNODE * NC;
    const float* __restrict__ prow = posf + b * NNODE * 4;

#pragma unroll 2
    for (int n = 0; n < nn; ++n) {
        // wave-uniform -> s_load_dwordx4
        const float qx = prow[n * 4 + 0];
        const float qy = prow[n * 4 + 1];
        const float qz = prow[n * 4 + 2];
        const float qw = prow[n * 4 + 3];
        const float txy = fmaf(qx, gx, fmaf(qy, gy, qw));
        float w[KG];
#pragma unroll
        for (int j = 0; j < KG; ++j) {
            const float t = fmaf(qz, gz[j], txy);
            // denom = s2 + max(d2,0) == max(t + g2 + s2, s2)
            w[j] = __builtin_amdgcn_rcpf(fmaxf(t + g2s2[j], s2));
        }
        const float* __restrict__ r = nrow + n * NC;  // wave-uniform row
#pragma unroll
        for (int c = 0; c < NC; ++c) {
            const float v = r[c];                     // s_load, SGPR operand
#pragma unroll
            for (int j = 0; j < KG; ++j)
                acc[j][c] = fmaf(w[j], v, acc[j][c]);
        }
    }

    // output base: (b, c, ix, iy, iz0)
    float* __restrict__ o = outp + (size_t)(b * NC) * G + ((ix << LOG) + iy) * NX + iz0;

    if constexpr (STAGE == 0) {
#pragma unroll
        for (int c = 0; c < NC; ++c) {
            f32x4 r;
            r.x = acc[0][c]; r.y = acc[1][c]; r.z = acc[2][c]; r.w = acc[3][c];
            *reinterpret_cast<f32x4*>(&o[(size_t)c * G]) = r;
        }
    } else {
        constexpr int NH = NX / 2;
        constexpr int GH = NH * NH * NH;
        // half-pixel 2x upsample: even o -> (m-1,m)@(0.25,0.75);
        // odd o -> (m,m+1)@(0.75,0.25); edge-clamped.
        int x0i = (ix >> 1) - 1 + (ix & 1); int x1i = x0i + 1;
        int y0i = (iy >> 1) - 1 + (iy & 1); int y1i = y0i + 1;
        const float wxl = (ix & 1) ? 0.75f : 0.25f;
        const float wyl = (iy & 1) ? 0.75f : 0.25f;
        if (x0i < 0) x0i = 0; if (x1i > NH - 1) x1i = NH - 1;
        if (y0i < 0) y0i = 0; if (y1i > NH - 1) y1i = NH - 1;
        const float wxh = 1.0f - wxl, wyh = 1.0f - wyl;
        const float w00 = wxl * wyl, w01 = wxl * wyh;
        const float w10 = wxh * wyl, w11 = wxh * wyh;

        // distinct z sources for outputs iz0..iz0+3 (iz0 = 4k):
        // zs = clamp(2k-1 .. 2k+2); outputs:
        // j0: .25*v[0] + .75*v[1]; j1: .75*v[1] + .25*v[2];
        // j2: .25*v[1] + .75*v[2]; j3: .75*v[2] + .25*v[3]
        const int k2 = iz0 >> 1;  // 2k
        int zs[4];
        zs[0] = k2 - 1 < 0 ? 0 : k2 - 1;
        zs[1] = k2;
        zs[2] = k2 + 1;
        zs[3] = k2 + 2 > NH - 1 ? NH - 1 : k2 + 2;

        const int r00 = (x0i * NH + y0i) * NH;
        const int r01 = (x0i * NH + y1i) * NH;
        const int r10 = (x1i * NH + y0i) * NH;
        const int r11 = (x1i * NH + y1i) * NH;

        const float* __restrict__ pb = prev + (size_t)(b * NC) * GH;
#pragma unroll
        for (int c = 0; c < NC; ++c) {
            const float* __restrict__ pc = pb + (size_t)c * GH;
            float v[4];
#pragma unroll
            for (int zi = 0; zi < 4; ++zi) {
                const int z = zs[zi];
                v[zi] = w00 * pc[r00 + z] + w01 * pc[r01 + z]
                      + w10 * pc[r10 + z] + w11 * pc[r11 + z];
            }
            f32x4 r;
            r.x = fmaf(0.25f, v[0], fmaf(0.75f, v[1], acc[0][c]));
            r.y = fmaf(0.75f, v[1], fmaf(0.25f, v[2], acc[1][c]));
            r.z = fmaf(0.25f, v[1], fmaf(0.75f, v[2], acc[2][c]));
            r.w = fmaf(0.75f, v[2], fmaf(0.25f, v[3], acc[3][c]));
            if constexpr (STAGE == 2)
                __builtin_nontemporal_store(r, reinterpret_cast<f32x4*>(&o[(size_t)c * G]));
            else
                *reinterpret_cast<f32x4*>(&o[(size_t)c * G]) = r;
        }
    }
}

extern "C" void kernel_launch(void* const* d_in, const int* in_sizes, int n_in,
                              void* d_out, int out_size, void* d_ws, size_t ws_size,
                              hipStream_t stream) {
    const float* pos           = (const float*)d_in[0];
    const float* node_features = (const float*)d_in[1];
    const float* origin        = (const float*)d_in[2];
    const float* lattice       = (const float*)d_in[3];
    const int*   batch_nodes   = (const int*)d_in[4];
    const float* Wp            = (const float*)d_in[5];
    const float* bp            = (const float*)d_in[6];
    const float* scale         = (const float*)d_in[7];
    float* out = (float*)d_out;

    float* wsf = (float*)d_ws;
    float* nf   = wsf;                                 // 3*8*64*32 = 49152 floats
    float* posf = wsf + 49152;                         // 8*64*4    = 2048
    float* x0 = posf + 2048;                           // 8*32*4096  = 1048576
    float* x1 = x0 + (size_t)NB * NC * 16 * 16 * 16;   // 8*32*32768 = 8388608

    nf_kernel<<<dim3(192), dim3(256), 0, stream>>>(node_features, Wp, bp, scale,
                                                   pos, nf, posf);

    stage_kernel<0, 16><<<dim3(NB * 4096 / KG / 256), dim3(256), 0, stream>>>(
        posf, origin, lattice, batch_nodes, scale, nf, (const float*)nullptr, x0);

    stage_kernel<1, 32><<<dim3(NB * 32768 / KG / 256), dim3(256), 0, stream>>>(
        posf, origin, lattice, batch_nodes, scale, nf, x0, x1);

    stage_kernel<2, 64><<<dim3(NB * 262144 / KG / 256), dim3(256), 0, stream>>>(
        posf, origin, lattice, batch_nodes, scale, nf, x1, out);
}